// Round 5
// baseline (1594.919 us; speedup 1.0000x reference)
//
#include <hip/hip_runtime.h>
#include <hip/hip_bf16.h>
#include <hip/hip_fp16.h>

// SVD-RNN: W = U diag(s) V from Householder chains; h_t = tanh(xp_t + W h_{t-1});
// out_t = h_t W_out^T + b_out.
#define BB 64
#define TT 2048
#define II 128
#define HH 256
#define OO 128
#define RCH 8                      // recurrence chunk length (global I/O batching)

typedef _Float16 f16x2 __attribute__((ext_vector_type(2)));

#if __has_builtin(__builtin_amdgcn_fdot2)
__device__ __forceinline__ float fdot2(f16x2 a, f16x2 b, float c) {
    return __builtin_amdgcn_fdot2(a, b, c, false);
}
#else
__device__ __forceinline__ float fdot2(f16x2 a, f16x2 b, float c) {
    return fmaf((float)a.x, (float)b.x, fmaf((float)a.y, (float)b.y, c));
}
#endif

__device__ __forceinline__ f16x2 u2h(unsigned int u) { return __builtin_bit_cast(f16x2, u); }
__device__ __forceinline__ unsigned int packf16(float a, float b) {
    return __builtin_bit_cast(unsigned int, f16x2{(_Float16)a, (_Float16)b});
}

__device__ __forceinline__ float tanh_fast(float x) {
    float xc = fminf(fmaxf(x, -9.0f), 9.0f);
    float e = __expf(2.0f * xc);
    return (e - 1.0f) * __fdividef(1.0f, e + 1.0f);
}

// ---------------------------------------------------------------------------
// Kernel 1: masked+flipped Householder vectors and betas.
// ---------------------------------------------------------------------------
__global__ __launch_bounds__(64) void prep_kernel(
    const float* __restrict__ u_raw, const float* __restrict__ v_raw,
    float* __restrict__ u_eff, float* __restrict__ v_eff,
    float* __restrict__ beta_u, float* __restrict__ beta_v)
{
    const int row = blockIdx.x;
    const int lane = threadIdx.x;
    const bool isU = row < HH;
    const int i = isU ? row : row - HH;
    const float* src = isU ? (u_raw + (size_t)i * HH) : (v_raw + (size_t)(HH - 1 - i) * HH);
    float* dst = (isU ? u_eff : v_eff) + (size_t)i * HH;
    const int lo = isU ? (HH - 1 - i) : i;
    float ss = 0.0f;
    for (int c = lane; c < HH; c += 64) {
        float vv = (c >= lo) ? src[HH - 1 - c] : 0.0f;
        dst[c] = vv;
        ss += vv * vv;
    }
    for (int m = 1; m < 64; m <<= 1) ss += __shfl_xor(ss, m, 64);
    if (lane == 0) (isU ? beta_u : beta_v)[i] = 2.0f / ss;
}

// ---------------------------------------------------------------------------
// Kernel 2: Householder chain per column.
// ---------------------------------------------------------------------------
__global__ __launch_bounds__(256) void hh_kernel(
    const float* __restrict__ u_eff, const float* __restrict__ v_eff,
    const float* __restrict__ beta_u, const float* __restrict__ beta_v,
    float* __restrict__ Ucol, float* __restrict__ Vrow)
{
    const int wid = blockIdx.x * 4 + (threadIdx.x >> 6);
    const int lane = threadIdx.x & 63;
    const bool isU = wid < HH;
    const int j = isU ? wid : wid - HH;
    const float* eff = isU ? u_eff : v_eff;
    const float* beta = isU ? beta_u : beta_v;

    float cr0 = (j == 4 * lane + 0) ? 1.0f : 0.0f;
    float cr1 = (j == 4 * lane + 1) ? 1.0f : 0.0f;
    float cr2 = (j == 4 * lane + 2) ? 1.0f : 0.0f;
    float cr3 = (j == 4 * lane + 3) ? 1.0f : 0.0f;

    const int i0 = isU ? (HH - 1 - j) : 0;
    for (int i = i0; i < HH; ++i) {
        const float4 v4 = *(const float4*)(eff + (size_t)i * HH + lane * 4);
        float d = v4.x * cr0 + v4.y * cr1 + v4.z * cr2 + v4.w * cr3;
        for (int m = 1; m < 64; m <<= 1) d += __shfl_xor(d, m, 64);
        const float t = beta[i] * d;
        cr0 = fmaf(-t, v4.x, cr0);
        cr1 = fmaf(-t, v4.y, cr1);
        cr2 = fmaf(-t, v4.z, cr2);
        cr3 = fmaf(-t, v4.w, cr3);
    }
    if (isU) {
        *(float4*)(Ucol + (size_t)j * HH + lane * 4) = make_float4(cr0, cr1, cr2, cr3);
    } else {
        Vrow[(size_t)(4 * lane + 0) * HH + j] = cr0;
        Vrow[(size_t)(4 * lane + 1) * HH + j] = cr1;
        Vrow[(size_t)(4 * lane + 2) * HH + j] = cr2;
        Vrow[(size_t)(4 * lane + 3) * HH + j] = cr3;
    }
}

// ---------------------------------------------------------------------------
// Kernel 3: W[r][c] = sum_k Ucol[k][r] * sig[k] * Vrow[k][c]
// ---------------------------------------------------------------------------
__global__ __launch_bounds__(256) void w_kernel(
    const float* __restrict__ Ucol, const float* __restrict__ Vrow,
    const float* __restrict__ sig, float* __restrict__ Wm)
{
    const int r = blockIdx.x;
    const int c = threadIdx.x;
    float acc = 0.0f;
    #pragma unroll 4
    for (int k = 0; k < HH; ++k) {
        acc = fmaf(Ucol[(size_t)k * HH + r] * sig[k], Vrow[(size_t)k * HH + c], acc);
    }
    Wm[(size_t)r * HH + c] = acc;
}

// ---------------------------------------------------------------------------
// Tiled GEMM with bias, f16x2/dot2 inner: C[M][N] = A[M][K]*B[N][K]^T + bias.
// ---------------------------------------------------------------------------
__device__ __forceinline__ uint4 stage8(const float* p) {
    float4 a = *(const float4*)p;
    float4 b = *(const float4*)(p + 4);
    return make_uint4(packf16(a.x, a.y), packf16(a.z, a.w),
                      packf16(b.x, b.y), packf16(b.z, b.w));
}
__device__ __forceinline__ uint4 stage8(const __half* p) {
    return *(const uint4*)p;
}
__device__ __forceinline__ void storeC(float* p, float v) { *p = v; }
__device__ __forceinline__ void storeC(__half* p, float v) { *p = __float2half_rn(v); }

template <typename AT, typename OT>
__global__ __launch_bounds__(256) void gemm_bias(
    const AT* __restrict__ A, const float* __restrict__ Bm,
    const float* __restrict__ bias, OT* __restrict__ C,
    int M, int N, int K)
{
    __shared__ unsigned int As[64][20];
    __shared__ unsigned int Bs[64][20];
    const int m0 = blockIdx.x * 64;
    const int n0 = blockIdx.y * 64;
    const int tid = threadIdx.x;
    const int lr = tid >> 2;
    const int lc = (tid & 3) << 3;
    const int tm = tid >> 4;
    const int tn = tid & 15;
    float acc[4][4] = {};
    for (int k0 = 0; k0 < K; k0 += 32) {
        *(uint4*)&As[lr][lc >> 1] = stage8(A + (size_t)(m0 + lr) * K + k0 + lc);
        *(uint4*)&Bs[lr][lc >> 1] = stage8(Bm + (size_t)(n0 + lr) * K + k0 + lc);
        __syncthreads();
        #pragma unroll
        for (int k8 = 0; k8 < 4; ++k8) {
            uint4 a4[4], b4[4];
            #pragma unroll
            for (int r = 0; r < 4; ++r) {
                a4[r] = *(const uint4*)&As[tm * 4 + r][k8 * 4];
                b4[r] = *(const uint4*)&Bs[tn + 16 * r][k8 * 4];
            }
            #pragma unroll
            for (int i2 = 0; i2 < 4; ++i2) {
                #pragma unroll
                for (int j2 = 0; j2 < 4; ++j2) {
                    acc[i2][j2] = fdot2(u2h(a4[i2].x), u2h(b4[j2].x), acc[i2][j2]);
                    acc[i2][j2] = fdot2(u2h(a4[i2].y), u2h(b4[j2].y), acc[i2][j2]);
                    acc[i2][j2] = fdot2(u2h(a4[i2].z), u2h(b4[j2].z), acc[i2][j2]);
                    acc[i2][j2] = fdot2(u2h(a4[i2].w), u2h(b4[j2].w), acc[i2][j2]);
                }
            }
        }
        __syncthreads();
    }
    #pragma unroll
    for (int j2 = 0; j2 < 4; ++j2) {
        const int n = n0 + tn + 16 * j2;
        const float bv = bias[n];
        #pragma unroll
        for (int i2 = 0; i2 < 4; ++i2) {
            const int m = m0 + tm * 4 + i2;
            storeC(C + (size_t)m * N + n, acc[i2][j2] + bv);
        }
    }
}

// ---------------------------------------------------------------------------
// Kernel 5: recurrence. 64 WGs (1/batch) x 512 threads (8 waves).
// R4 RESTRUCTURE — ONE barrier per step, h never leaves the wave:
//  * Wave q's k-slice [32q,32q+32) == the rows wave q reduces. After the
//    reduction the wave holds its next-step h input in registers; broadcast
//    across lanes via v_readlane (VALU), not LDS. No h round-trip, no 2nd
//    barrier (R0-R3 had 2 barriers + 2 LDS latencies/step, stuck ~1380 cyc).
//  * ps double-buffered by step parity: a wave writing step s+1 partials
//    (buffer p^1) can't clobber buffer p that a slower wave still reads,
//    and it can't reach buffer p again without passing the next barrier.
//  * Phase2: lanes l / l+32 each sum 4 of the 8 slabs for row 32q+(l&31)
//    (4 conflict-free ds_read_b32), shfl_xor(32) combines; + xp; tanh;
//    pack even/odd rows to f16x2; 16x readlane -> next hv[16].
//  * Global I/O chunked (RCH=8): xp preloaded per chunk, h stored per chunk.
// NO LDS atomics (R1: same-address ds atomics serialize, 8.6x regression).
// ---------------------------------------------------------------------------
__global__ __launch_bounds__(512) void recur_kernel(
    const float* __restrict__ Wm,              // [256][256] f32 row-major
    const __half* __restrict__ xp,             // [B][T][256] f16
    __half* __restrict__ hall)                 // [B][T][256] f16
{
    const int b = blockIdx.x;
    const int tid = threadIdx.x;
    const int l = tid & 63;
    const int q = tid >> 6;        // wave 0..7
    const int lr = l & 31;         // row-local index within wave's 32-row slice
    const int half = l >> 5;       // slab half (0: slabs 0-3, 1: slabs 4-7)
    const int row = 32 * q + lr;   // this lane's owned row (duplicated l/l+32)

    __shared__ float ps[2][8][HH]; // double-buffered partials, 16 KB

    // W fragment: rows 4l..4l+3, cols q*32..q*32+32, as f16 pairs (64 VGPRs).
    f16x2 w2[4][16];
    #pragma unroll
    for (int r = 0; r < 4; ++r) {
        const float* Wp = Wm + (size_t)(4 * l + r) * HH + q * 32;
        #pragma unroll
        for (int c4 = 0; c4 < 8; ++c4) {
            float4 f = *(const float4*)(Wp + c4 * 4);
            w2[r][c4 * 2 + 0] = f16x2{(_Float16)f.x, (_Float16)f.y};
            w2[r][c4 * 2 + 1] = f16x2{(_Float16)f.z, (_Float16)f.w};
        }
    }

    const unsigned short* xpw16 = (const unsigned short*)(xp + (size_t)b * TT * HH);
    unsigned short* hw16 = (unsigned short*)(hall + (size_t)b * TT * HH);

    unsigned short xpcur[RCH], xpnxt[RCH], hst[RCH];
    if (half == 0) {
        #pragma unroll
        for (int s = 0; s < RCH; ++s) xpcur[s] = xpw16[(size_t)s * HH + row];
    }

    // next-step h input for this wave's k-slice, wave-uniform, f16x2 pairs
    f16x2 hv[16];
    #pragma unroll
    for (int i = 0; i < 16; ++i) hv[i] = f16x2{(_Float16)0.f, (_Float16)0.f};

    const int nch = TT / RCH;
    for (int c = 0; c < nch; ++c) {
        #pragma unroll
        for (int s = 0; s < RCH; ++s) {
            const int p = s & 1;
            // prefetch next chunk's xp under step-0 compute
            if (s == 0 && half == 0 && c + 1 < nch) {
                const unsigned short* xn = xpw16 + (size_t)(c + 1) * RCH * HH + row;
                #pragma unroll
                for (int s2 = 0; s2 < RCH; ++s2) xpnxt[s2] = xn[(size_t)s2 * HH];
            }
            // phase 1: dot2 over this wave's k-slice, h from registers
            float a0 = 0.f, a1 = 0.f, a2 = 0.f, a3 = 0.f;
            #pragma unroll
            for (int cc = 0; cc < 16; ++cc) {
                a0 = fdot2(w2[0][cc], hv[cc], a0);
                a1 = fdot2(w2[1][cc], hv[cc], a1);
                a2 = fdot2(w2[2][cc], hv[cc], a2);
                a3 = fdot2(w2[3][cc], hv[cc], a3);
            }
            *(float4*)(&ps[p][q][4 * l]) = make_float4(a0, a1, a2, a3);
            __syncthreads();   // the ONLY barrier per step

            // phase 2: reduce own rows. lane l sums slabs 4*half..4*half+3.
            const float* pb = &ps[p][4 * half][row];
            float r0 = pb[0 * HH], r1 = pb[1 * HH], r2 = pb[2 * HH], r3 = pb[3 * HH];
            float s4 = (r0 + r1) + (r2 + r3);
            float tot = s4 + __shfl_xor(s4, 32, 64);
            float xv = 0.f;
            if (half == 0) {
                __half_raw hr; hr.x = xpcur[s];
                xv = (float)(*(const _Float16*)&hr.x);
            }
            float hn = tanh_fast(tot + xv);
            if (half == 0) {
                f16x2 t2{(_Float16)hn, (_Float16)0.f};
                hst[s] = (unsigned short)(__builtin_bit_cast(unsigned int, t2) & 0xffffu);
            }
            // pack row pairs and broadcast to all lanes (VALU, no LDS/barrier)
            float hn1 = __shfl_down(hn, 1, 64);
            unsigned int packed = packf16(hn, hn1);  // valid at even lanes < 32
            #pragma unroll
            for (int i = 0; i < 16; ++i) {
                hv[i] = u2h((unsigned int)__builtin_amdgcn_readlane(packed, 2 * i));
            }
        }
        // chunk epilogue: store 8 h steps (lanes<32), rotate xp buffers
        if (half == 0) {
            unsigned short* hwc = hw16 + (size_t)c * RCH * HH + row;
            #pragma unroll
            for (int s = 0; s < RCH; ++s) hwc[(size_t)s * HH] = hst[s];
            #pragma unroll
            for (int s = 0; s < RCH; ++s) xpcur[s] = xpnxt[s];
        }
    }
}

// ---------------------------------------------------------------------------
extern "C" void kernel_launch(void* const* d_in, const int* in_sizes, int n_in,
                              void* d_out, int out_size, void* d_ws, size_t ws_size,
                              hipStream_t stream) {
    const float* x     = (const float*)d_in[0];   // [B][T][I]
    const float* W_in  = (const float*)d_in[1];   // [H][I]
    const float* b_in  = (const float*)d_in[2];   // [H]
    const float* W_out = (const float*)d_in[3];   // [O][H]
    const float* b_out = (const float*)d_in[4];   // [O]
    const float* u_raw = (const float*)d_in[5];   // [M][H]
    const float* sig   = (const float*)d_in[6];   // [H]
    const float* v_raw = (const float*)d_in[7];   // [M][H]
    float* out = (float*)d_out;                   // [B][T][O]

    char* ws = (char*)d_ws;
    size_t off = 0;
    auto alloc = [&](size_t bytes) -> void* {
        void* p = (void*)(ws + off);
        off += (bytes + 255) & ~((size_t)255);
        return p;
    };
    float* u_eff  = (float*)alloc((size_t)HH * HH * 4);
    float* v_eff  = (float*)alloc((size_t)HH * HH * 4);
    float* beta_u = (float*)alloc((size_t)HH * 4);
    float* beta_v = (float*)alloc((size_t)HH * 4);
    float* Ucol   = (float*)alloc((size_t)HH * HH * 4);
    float* Vrow   = (float*)alloc((size_t)HH * HH * 4);
    float* Wm     = (float*)alloc((size_t)HH * HH * 4);
    __half* xpbuf = (__half*)alloc((size_t)BB * TT * HH * 2);
    __half* hall  = (__half*)alloc((size_t)BB * TT * HH * 2);
    (void)ws_size; (void)in_sizes; (void)n_in; (void)out_size;

    prep_kernel<<<2 * HH, 64, 0, stream>>>(u_raw, v_raw, u_eff, v_eff, beta_u, beta_v);
    hh_kernel<<<(2 * HH) / 4, 256, 0, stream>>>(u_eff, v_eff, beta_u, beta_v, Ucol, Vrow);
    w_kernel<<<HH, HH, 0, stream>>>(Ucol, Vrow, sig, Wm);
    gemm_bias<float, __half>
        <<<dim3((BB * TT) / 64, HH / 64), 256, 0, stream>>>(x, W_in, b_in, xpbuf, BB * TT, HH, II);
    recur_kernel<<<BB, 512, 0, stream>>>(Wm, xpbuf, hall);
    gemm_bias<__half, float>
        <<<dim3((BB * TT) / 64, OO / 64), 256, 0, stream>>>(hall, W_out, b_out, out, BB * TT, OO, HH);
}